// Round 1
// baseline (539.443 us; speedup 1.0000x reference)
//
#include <hip/hip_runtime.h>

#define N_NODES 50000
#define HIDDEN  64
#define N_EDGES 1200000

__device__ __forceinline__ float bcastf(float v, int k) {
    return __int_as_float(__builtin_amdgcn_readlane(__float_as_int(v), k));
}

// ---------------- CSR build ----------------

__global__ __launch_bounds__(256) void hist_kernel(const int* __restrict__ ei,
                                                   int* __restrict__ deg, int E) {
    int e = blockIdx.x * 256 + threadIdx.x;
    if (e < E) atomicAdd(&deg[ei[E + e]], 1);
}

// per-block exclusive scan (writes block-local exclusive into row_ptr, block sum into bsums)
__global__ __launch_bounds__(1024) void scan1_kernel(const int* __restrict__ deg,
                                                     int* __restrict__ excl,
                                                     int* __restrict__ bsums, int n) {
    int tid = threadIdx.x;
    int i = blockIdx.x * 1024 + tid;
    int lane = tid & 63, w = tid >> 6;
    int v = (i < n) ? deg[i] : 0;
    int x = v;
#pragma unroll
    for (int o = 1; o < 64; o <<= 1) { int y = __shfl_up(x, o); if (lane >= o) x += y; }
    __shared__ int wsum[16];
    if (lane == 63) wsum[w] = x;
    __syncthreads();
    if (w == 0) {
        int s = (lane < 16) ? wsum[lane] : 0;
#pragma unroll
        for (int o = 1; o < 16; o <<= 1) { int y = __shfl_up(s, o); if (lane >= o) s += y; }
        if (lane < 16) wsum[lane] = s;
    }
    __syncthreads();
    int wofs = (w > 0) ? wsum[w - 1] : 0;
    int incl = x + wofs;
    if (i < n) excl[i] = incl - v;
    if (tid == 1023) bsums[blockIdx.x] = incl;
}

// exclusive scan of block sums (nb <= 64)
__global__ void scan2_kernel(int* bsums, int nb) {
    int lane = threadIdx.x;
    int v = (lane < nb) ? bsums[lane] : 0;
    int x = v;
#pragma unroll
    for (int o = 1; o < 64; o <<= 1) { int y = __shfl_up(x, o); if (lane >= o) x += y; }
    if (lane < nb) bsums[lane] = x - v;
}

// add block offsets; produce row_ptr and cursor copy
__global__ __launch_bounds__(1024) void scan3_kernel(int* __restrict__ row_ptr,
                                                     const int* __restrict__ bsums,
                                                     int* __restrict__ cursor, int n, int E) {
    int i = blockIdx.x * 1024 + threadIdx.x;
    if (i < n) {
        int v = row_ptr[i] + bsums[blockIdx.x];
        row_ptr[i] = v;
        cursor[i] = v;
    }
    if (i == 0) row_ptr[n] = E;
}

__global__ __launch_bounds__(256) void scatter_kernel(const int* __restrict__ ei,
                                                      int* __restrict__ cursor,
                                                      int* __restrict__ csr_src, int E) {
    int e = blockIdx.x * 256 + threadIdx.x;
    if (e < E) {
        int dst = ei[E + e];
        int pos = atomicAdd(&cursor[dst], 1);
        csr_src[pos] = ei[e];
    }
}

// ---------------- dense GEMMs: t = h@Wnbr ; u = h@Wself + b ----------------
// one wave per row (grid-stride); W columns held in registers (lane j = output col j),
// row elements broadcast with v_readlane (no LDS, no DS traffic).
__global__ __launch_bounds__(256) void gemm2_kernel(const float* __restrict__ h,
                                                    const float* __restrict__ Wnbr,
                                                    const float* __restrict__ Wself,
                                                    const float* __restrict__ bias,
                                                    float* __restrict__ t,
                                                    float* __restrict__ u, int n) {
    int lane = threadIdx.x & 63;
    float wn[64], ws[64];
#pragma unroll
    for (int k = 0; k < 64; ++k) {
        wn[k] = Wnbr[k * 64 + lane];
        ws[k] = Wself[k * 64 + lane];
    }
    float bv = bias[lane];
    int wave = (blockIdx.x * 256 + threadIdx.x) >> 6;
    int nwaves = gridDim.x * 4;
    for (int i = wave; i < n; i += nwaves) {
        float hv = h[i * 64 + lane];
        float tacc = 0.f, uacc = bv;
#pragma unroll
        for (int k = 0; k < 64; ++k) {
            float hk = bcastf(hv, k);
            tacc = fmaf(hk, wn[k], tacc);
            uacc = fmaf(hk, ws[k], uacc);
        }
        t[i * 64 + lane] = tacc;
        u[i * 64 + lane] = uacc;
    }
}

// ---------------- gather-aggregate + epilogue ----------------
// one wave per dst node; lane j = channel j. out = relu(u + (sum t[src]) * (mean? 1/deg : 1))
__global__ __launch_bounds__(256) void agg_kernel(const float* __restrict__ t,
                                                  const float* __restrict__ u,
                                                  const int* __restrict__ row_ptr,
                                                  const int* __restrict__ csr_src,
                                                  float* __restrict__ out, int n, int use_mean) {
    int lane = threadIdx.x & 63;
    int node = (blockIdx.x * 256 + threadIdx.x) >> 6;
    if (node >= n) return;
    int start = row_ptr[node];
    int end = row_ptr[node + 1];
    float acc = 0.f;
    int e = start;
    while (e < end) {
        int cnt = end - e;
        if (cnt > 64) cnt = 64;
        // one coalesced batch-load of up to 64 src indices, broadcast via readlane
        int idx = (lane < cnt) ? csr_src[e + lane] : 0;
        int j = 0;
        float a0 = 0.f, a1 = 0.f, a2 = 0.f, a3 = 0.f;
        for (; j + 4 <= cnt; j += 4) {
            int s0 = __builtin_amdgcn_readlane(idx, j);
            int s1 = __builtin_amdgcn_readlane(idx, j + 1);
            int s2 = __builtin_amdgcn_readlane(idx, j + 2);
            int s3 = __builtin_amdgcn_readlane(idx, j + 3);
            a0 += t[(size_t)s0 * 64 + lane];
            a1 += t[(size_t)s1 * 64 + lane];
            a2 += t[(size_t)s2 * 64 + lane];
            a3 += t[(size_t)s3 * 64 + lane];
        }
        for (; j < cnt; ++j) {
            int s = __builtin_amdgcn_readlane(idx, j);
            a0 += t[(size_t)s * 64 + lane];
        }
        acc += (a0 + a1) + (a2 + a3);
        e += cnt;
    }
    float res = u[(size_t)node * 64 + lane];
    if (use_mean) {
        float c = (float)(end - start);
        res += acc / fmaxf(c, 1.f);
    } else {
        res += acc;
    }
    out[(size_t)node * 64 + lane] = fmaxf(res, 0.f);
}

// ---------------- launch ----------------

extern "C" void kernel_launch(void* const* d_in, const int* in_sizes, int n_in,
                              void* d_out, int out_size, void* d_ws, size_t ws_size,
                              hipStream_t stream) {
    const float* x      = (const float*)d_in[0];
    const int*   ei     = (const int*)d_in[1];   // [2, E] int32
    const float* Wrel1  = (const float*)d_in[2];
    const float* Wroot1 = (const float*)d_in[3];
    const float* b1     = (const float*)d_in[4];
    const float* Wself2 = (const float*)d_in[5];
    const float* Wnbr2  = (const float*)d_in[6];
    const float* b2     = (const float*)d_in[7];
    const float* Wself3 = (const float*)d_in[8];
    const float* Wnbr3  = (const float*)d_in[9];
    const float* b3     = (const float*)d_in[10];
    const float* Wself4 = (const float*)d_in[11];
    const float* Wnbr4  = (const float*)d_in[12];
    const float* b4     = (const float*)d_in[13];

    const int N = N_NODES, E = N_EDGES;

    auto align = [](size_t o) { return (o + 255) & ~(size_t)255; };
    char* base = (char*)d_ws;
    size_t off = 0;
    int* deg     = (int*)(base + off); off = align(off + (size_t)N * 4);
    int* row_ptr = (int*)(base + off); off = align(off + (size_t)(N + 1) * 4);
    int* cursor  = (int*)(base + off); off = align(off + (size_t)N * 4);
    int* bsums   = (int*)(base + off); off = align(off + 64 * 4);
    int* csr_src = (int*)(base + off); off = align(off + (size_t)E * 4);
    float* t  = (float*)(base + off); off = align(off + (size_t)N * 64 * 4);
    float* u  = (float*)(base + off); off = align(off + (size_t)N * 64 * 4);
    float* h1 = (float*)(base + off); off = align(off + (size_t)N * 64 * 4);

    float* out1 = (float*)d_out;                      // x_1
    float* out2 = (float*)d_out + (size_t)N * 64;     // x_2

    // CSR build (deg must start at 0: ws is poisoned each call)
    hipMemsetAsync(deg, 0, (size_t)N * 4, stream);
    hist_kernel<<<(E + 255) / 256, 256, 0, stream>>>(ei, deg, E);
    int nb = (N + 1023) / 1024;  // 49 <= 64
    scan1_kernel<<<nb, 1024, 0, stream>>>(deg, row_ptr, bsums, N);
    scan2_kernel<<<1, 64, 0, stream>>>(bsums, nb);
    scan3_kernel<<<nb, 1024, 0, stream>>>(row_ptr, bsums, cursor, N, E);
    scatter_kernel<<<(E + 255) / 256, 256, 0, stream>>>(ei, cursor, csr_src, E);

    const int GB = 400;            // gemm blocks (1600 waves, ~31 rows each)
    const int AB = (N + 3) / 4;    // 12500 blocks = 50000 waves, exact

    // Layer 1 (RGCN): u = x@W_root1 + b1 ; t = x@W_rel1 ; mean aggregate
    gemm2_kernel<<<GB, 256, 0, stream>>>(x, Wrel1, Wroot1, b1, t, u, N);
    agg_kernel<<<AB, 256, 0, stream>>>(t, u, row_ptr, csr_src, h1, N, 1);
    // Layer 2 (GraphConv) -> x_1
    gemm2_kernel<<<GB, 256, 0, stream>>>(h1, Wnbr2, Wself2, b2, t, u, N);
    agg_kernel<<<AB, 256, 0, stream>>>(t, u, row_ptr, csr_src, out1, N, 0);
    // Layer 3
    gemm2_kernel<<<GB, 256, 0, stream>>>(out1, Wnbr3, Wself3, b3, t, u, N);
    agg_kernel<<<AB, 256, 0, stream>>>(t, u, row_ptr, csr_src, h1, N, 0);
    // Layer 4 -> x_2
    gemm2_kernel<<<GB, 256, 0, stream>>>(h1, Wnbr4, Wself4, b4, t, u, N);
    agg_kernel<<<AB, 256, 0, stream>>>(t, u, row_ptr, csr_src, out2, N, 0);
}

// Round 2
// 435.017 us; speedup vs baseline: 1.2401x; 1.2401x over previous
//
#include <hip/hip_runtime.h>

#define N_NODES 50000
#define HIDDEN  64
#define N_EDGES 1200000

#define BSHIFT 8                      // 256 nodes per bucket
#define NBUK   196                    // ceil(50000/256)
#define GBIN   256                    // blocks for bin_count/bin_scatter
#define NCOUNT (NBUK * GBIN)          // 50176
#define CAP    8192                   // LDS staging capacity (edges per bucket)

__device__ __forceinline__ float bcastf(float v, int k) {
    return __int_as_float(__builtin_amdgcn_readlane(__float_as_int(v), k));
}

// ---------------- bucketed CSR build ----------------

// per-block histogram over dst buckets; counts is bucket-major: counts[b*GBIN + blk]
__global__ __launch_bounds__(256) void bin_count_kernel(const int* __restrict__ ei,
                                                        int* __restrict__ counts, int E) {
    __shared__ int h[NBUK];
    int tid = threadIdx.x;
    if (tid < NBUK) h[tid] = 0;
    __syncthreads();
    for (int e = blockIdx.x * 256 + tid; e < E; e += GBIN * 256)
        atomicAdd(&h[ei[E + e] >> BSHIFT], 1);
    __syncthreads();
    if (tid < NBUK) counts[tid * GBIN + blockIdx.x] = h[tid];
}

// per-block exclusive scan (block-local exclusive into excl, block sum into bsums)
__global__ __launch_bounds__(1024) void scan1_kernel(const int* __restrict__ in,
                                                     int* __restrict__ excl,
                                                     int* __restrict__ bsums, int n) {
    int tid = threadIdx.x;
    int i = blockIdx.x * 1024 + tid;
    int lane = tid & 63, w = tid >> 6;
    int v = (i < n) ? in[i] : 0;
    int x = v;
#pragma unroll
    for (int o = 1; o < 64; o <<= 1) { int y = __shfl_up(x, o); if (lane >= o) x += y; }
    __shared__ int wsum[16];
    if (lane == 63) wsum[w] = x;
    __syncthreads();
    if (w == 0) {
        int s = (lane < 16) ? wsum[lane] : 0;
#pragma unroll
        for (int o = 1; o < 16; o <<= 1) { int y = __shfl_up(s, o); if (lane >= o) s += y; }
        if (lane < 16) wsum[lane] = s;
    }
    __syncthreads();
    int wofs = (w > 0) ? wsum[w - 1] : 0;
    int incl = x + wofs;
    if (i < n) excl[i] = incl - v;
    if (tid == 1023) bsums[blockIdx.x] = incl;
}

// exclusive scan of block sums (nb <= 64)
__global__ void scan2_kernel(int* bsums, int nb) {
    int lane = threadIdx.x;
    int v = (lane < nb) ? bsums[lane] : 0;
    int x = v;
#pragma unroll
    for (int o = 1; o < 64; o <<= 1) { int y = __shfl_up(x, o); if (lane >= o) x += y; }
    if (lane < nb) bsums[lane] = x - v;
}

// add block offsets in place
__global__ __launch_bounds__(1024) void scan3_kernel(int* __restrict__ a,
                                                     const int* __restrict__ bsums, int n) {
    int i = blockIdx.x * 1024 + threadIdx.x;
    if (i < n) a[i] += bsums[blockIdx.x];
}

// distribute (src,dst) pairs into bucket-grouped tmp using LDS cursors
__global__ __launch_bounds__(256) void bin_scatter_kernel(const int* __restrict__ ei,
                                                          const int* __restrict__ cex,
                                                          int2* __restrict__ tmp, int E) {
    __shared__ int cur[NBUK];
    int tid = threadIdx.x;
    if (tid < NBUK) cur[tid] = cex[tid * GBIN + blockIdx.x];
    __syncthreads();
    for (int e = blockIdx.x * 256 + tid; e < E; e += GBIN * 256) {
        int src = ei[e];
        int dst = ei[E + e];
        int p = atomicAdd(&cur[dst >> BSHIFT], 1);
        tmp[p] = make_int2(src, dst);
    }
}

// one block per bucket: local hist -> row_ptr, then place src into LDS stage, stream out
__global__ __launch_bounds__(256) void bucketize_kernel(const int2* __restrict__ tmp,
                                                        const int* __restrict__ cex,
                                                        int* __restrict__ row_ptr,
                                                        int* __restrict__ csr_src,
                                                        int n, int E) {
    __shared__ int hist[256];
    __shared__ int cur[256];
    __shared__ int stage[CAP];
    int b = blockIdx.x, tid = threadIdx.x;
    int bstart = cex[b * GBIN];
    int bend = (b == NBUK - 1) ? E : cex[(b + 1) * GBIN];
    int cnt = bend - bstart;
    int node_base = b << BSHIFT;

    hist[tid] = 0;
    __syncthreads();
    for (int i = tid; i < cnt; i += 256)
        atomicAdd(&hist[tmp[bstart + i].y - node_base], 1);
    __syncthreads();
    int v = hist[tid];
    // Hillis-Steele inclusive scan in place
#pragma unroll
    for (int o = 1; o < 256; o <<= 1) {
        __syncthreads();
        int y = (tid >= o) ? hist[tid - o] : 0;
        __syncthreads();
        hist[tid] += y;
    }
    __syncthreads();
    int excl = hist[tid] - v;
    cur[tid] = excl;
    int node = node_base + tid;
    if (node < n) row_ptr[node] = bstart + excl;
    if (b == NBUK - 1 && tid == 0) row_ptr[n] = E;
    __syncthreads();

    if (cnt <= CAP) {
        for (int i = tid; i < cnt; i += 256) {
            int2 p = tmp[bstart + i];
            int slot = atomicAdd(&cur[p.y - node_base], 1);
            stage[slot] = p.x;
        }
        __syncthreads();
        for (int i = tid; i < cnt; i += 256)
            csr_src[bstart + i] = stage[i];
    } else {  // safety fallback (never taken for uniform-random dst)
        for (int i = tid; i < cnt; i += 256) {
            int2 p = tmp[bstart + i];
            int slot = atomicAdd(&cur[p.y - node_base], 1);
            csr_src[bstart + slot] = p.x;
        }
    }
}

// ---------------- dense GEMMs: t = h@Wnbr ; u = h@Wself + b ----------------
__global__ __launch_bounds__(256) void gemm2_kernel(const float* __restrict__ h,
                                                    const float* __restrict__ Wnbr,
                                                    const float* __restrict__ Wself,
                                                    const float* __restrict__ bias,
                                                    float* __restrict__ t,
                                                    float* __restrict__ u, int n) {
    int lane = threadIdx.x & 63;
    float wn[64], ws[64];
#pragma unroll
    for (int k = 0; k < 64; ++k) {
        wn[k] = Wnbr[k * 64 + lane];
        ws[k] = Wself[k * 64 + lane];
    }
    float bv = bias[lane];
    int wave = (blockIdx.x * 256 + threadIdx.x) >> 6;
    int nwaves = gridDim.x * 4;
    for (int i = wave; i < n; i += nwaves) {
        float hv = h[i * 64 + lane];
        float tacc = 0.f, uacc = bv;
#pragma unroll
        for (int k = 0; k < 64; ++k) {
            float hk = bcastf(hv, k);
            tacc = fmaf(hk, wn[k], tacc);
            uacc = fmaf(hk, ws[k], uacc);
        }
        t[i * 64 + lane] = tacc;
        u[i * 64 + lane] = uacc;
    }
}

// ---------------- gather-aggregate + epilogue ----------------
__global__ __launch_bounds__(256) void agg_kernel(const float* __restrict__ t,
                                                  const float* __restrict__ u,
                                                  const int* __restrict__ row_ptr,
                                                  const int* __restrict__ csr_src,
                                                  float* __restrict__ out, int n, int use_mean) {
    int lane = threadIdx.x & 63;
    int node = (blockIdx.x * 256 + threadIdx.x) >> 6;
    if (node >= n) return;
    int start = row_ptr[node];
    int end = row_ptr[node + 1];
    float acc = 0.f;
    int e = start;
    while (e < end) {
        int cnt = end - e;
        if (cnt > 64) cnt = 64;
        int idx = (lane < cnt) ? csr_src[e + lane] : 0;
        int j = 0;
        float a0 = 0.f, a1 = 0.f, a2 = 0.f, a3 = 0.f;
        for (; j + 4 <= cnt; j += 4) {
            int s0 = __builtin_amdgcn_readlane(idx, j);
            int s1 = __builtin_amdgcn_readlane(idx, j + 1);
            int s2 = __builtin_amdgcn_readlane(idx, j + 2);
            int s3 = __builtin_amdgcn_readlane(idx, j + 3);
            a0 += t[(size_t)s0 * 64 + lane];
            a1 += t[(size_t)s1 * 64 + lane];
            a2 += t[(size_t)s2 * 64 + lane];
            a3 += t[(size_t)s3 * 64 + lane];
        }
        for (; j < cnt; ++j) {
            int s = __builtin_amdgcn_readlane(idx, j);
            a0 += t[(size_t)s * 64 + lane];
        }
        acc += (a0 + a1) + (a2 + a3);
        e += cnt;
    }
    float res = u[(size_t)node * 64 + lane];
    if (use_mean) {
        float c = (float)(end - start);
        res += acc / fmaxf(c, 1.f);
    } else {
        res += acc;
    }
    out[(size_t)node * 64 + lane] = fmaxf(res, 0.f);
}

// ---------------- launch ----------------

extern "C" void kernel_launch(void* const* d_in, const int* in_sizes, int n_in,
                              void* d_out, int out_size, void* d_ws, size_t ws_size,
                              hipStream_t stream) {
    const float* x      = (const float*)d_in[0];
    const int*   ei     = (const int*)d_in[1];   // [2, E] int32
    const float* Wrel1  = (const float*)d_in[2];
    const float* Wroot1 = (const float*)d_in[3];
    const float* b1     = (const float*)d_in[4];
    const float* Wself2 = (const float*)d_in[5];
    const float* Wnbr2  = (const float*)d_in[6];
    const float* b2     = (const float*)d_in[7];
    const float* Wself3 = (const float*)d_in[8];
    const float* Wnbr3  = (const float*)d_in[9];
    const float* b3     = (const float*)d_in[10];
    const float* Wself4 = (const float*)d_in[11];
    const float* Wnbr4  = (const float*)d_in[12];
    const float* b4     = (const float*)d_in[13];

    const int N = N_NODES, E = N_EDGES;

    auto align = [](size_t o) { return (o + 255) & ~(size_t)255; };
    char* base = (char*)d_ws;
    size_t off = 0;
    int* counts  = (int*)(base + off); off = align(off + (size_t)NCOUNT * 4);
    int* cex     = (int*)(base + off); off = align(off + (size_t)NCOUNT * 4);
    int* bsums   = (int*)(base + off); off = align(off + 64 * 4);
    int* row_ptr = (int*)(base + off); off = align(off + (size_t)(N + 1) * 4);
    int* csr_src = (int*)(base + off); off = align(off + (size_t)E * 4);
    float* t  = (float*)(base + off); off = align(off + (size_t)N * 64 * 4);
    float* u  = (float*)(base + off); off = align(off + (size_t)N * 64 * 4);
    float* h1 = (float*)(base + off); off = align(off + (size_t)N * 64 * 4);
    int2* tmp = (int2*)h1;  // alias: tmp dead before h1's first write (agg layer 1)

    float* out1 = (float*)d_out;                      // x_1
    float* out2 = (float*)d_out + (size_t)N * 64;     // x_2

    // ---- CSR build (no global atomics, no memset) ----
    bin_count_kernel<<<GBIN, 256, 0, stream>>>(ei, counts, E);
    int nb = (NCOUNT + 1023) / 1024;  // 49 <= 64
    scan1_kernel<<<nb, 1024, 0, stream>>>(counts, cex, bsums, NCOUNT);
    scan2_kernel<<<1, 64, 0, stream>>>(bsums, nb);
    scan3_kernel<<<nb, 1024, 0, stream>>>(cex, bsums, NCOUNT);
    bin_scatter_kernel<<<GBIN, 256, 0, stream>>>(ei, cex, tmp, E);
    bucketize_kernel<<<NBUK, 256, 0, stream>>>(tmp, cex, row_ptr, csr_src, N, E);

    const int GB = 400;            // gemm blocks (1600 waves)
    const int AB = (N + 3) / 4;    // 12500 blocks = 50000 waves

    // Layer 1 (RGCN): u = x@W_root1 + b1 ; t = x@W_rel1 ; mean aggregate
    gemm2_kernel<<<GB, 256, 0, stream>>>(x, Wrel1, Wroot1, b1, t, u, N);
    agg_kernel<<<AB, 256, 0, stream>>>(t, u, row_ptr, csr_src, h1, N, 1);
    // Layer 2 (GraphConv) -> x_1
    gemm2_kernel<<<GB, 256, 0, stream>>>(h1, Wnbr2, Wself2, b2, t, u, N);
    agg_kernel<<<AB, 256, 0, stream>>>(t, u, row_ptr, csr_src, out1, N, 0);
    // Layer 3
    gemm2_kernel<<<GB, 256, 0, stream>>>(out1, Wnbr3, Wself3, b3, t, u, N);
    agg_kernel<<<AB, 256, 0, stream>>>(t, u, row_ptr, csr_src, h1, N, 0);
    // Layer 4 -> x_2
    gemm2_kernel<<<GB, 256, 0, stream>>>(h1, Wnbr4, Wself4, b4, t, u, N);
    agg_kernel<<<AB, 256, 0, stream>>>(t, u, row_ptr, csr_src, out2, N, 0);
}

// Round 3
// 359.050 us; speedup vs baseline: 1.5024x; 1.2116x over previous
//
#include <hip/hip_runtime.h>

#define N_NODES 50000
#define HIDDEN  64
#define N_EDGES 1200000

#define BSHIFT 8                      // 256 nodes per bucket
#define NBUK   196                    // ceil(50000/256)
#define GBIN   256                    // blocks for bin_count/bin_scatter
#define NCOUNT (NBUK * GBIN)          // 50176
#define CAP    8192                   // LDS staging capacity (edges per bucket)

__device__ __forceinline__ float bcastf(float v, int k) {
    return __int_as_float(__builtin_amdgcn_readlane(__float_as_int(v), k));
}

// f32 -> bf16 (RNE) as ushort
__device__ __forceinline__ unsigned short f2bf(float x) {
    unsigned u = __float_as_uint(x);
    u += 0x7fffu + ((u >> 16) & 1u);
    return (unsigned short)(u >> 16);
}

// ---------------- bucketed CSR build ----------------

__global__ __launch_bounds__(256) void bin_count_kernel(const int* __restrict__ ei,
                                                        int* __restrict__ counts, int E) {
    __shared__ int h[NBUK];
    int tid = threadIdx.x;
    if (tid < NBUK) h[tid] = 0;
    __syncthreads();
    for (int e = blockIdx.x * 256 + tid; e < E; e += GBIN * 256)
        atomicAdd(&h[ei[E + e] >> BSHIFT], 1);
    __syncthreads();
    if (tid < NBUK) counts[tid * GBIN + blockIdx.x] = h[tid];
}

__global__ __launch_bounds__(1024) void scan1_kernel(const int* __restrict__ in,
                                                     int* __restrict__ excl,
                                                     int* __restrict__ bsums, int n) {
    int tid = threadIdx.x;
    int i = blockIdx.x * 1024 + tid;
    int lane = tid & 63, w = tid >> 6;
    int v = (i < n) ? in[i] : 0;
    int x = v;
#pragma unroll
    for (int o = 1; o < 64; o <<= 1) { int y = __shfl_up(x, o); if (lane >= o) x += y; }
    __shared__ int wsum[16];
    if (lane == 63) wsum[w] = x;
    __syncthreads();
    if (w == 0) {
        int s = (lane < 16) ? wsum[lane] : 0;
#pragma unroll
        for (int o = 1; o < 16; o <<= 1) { int y = __shfl_up(s, o); if (lane >= o) s += y; }
        if (lane < 16) wsum[lane] = s;
    }
    __syncthreads();
    int wofs = (w > 0) ? wsum[w - 1] : 0;
    int incl = x + wofs;
    if (i < n) excl[i] = incl - v;
    if (tid == 1023) bsums[blockIdx.x] = incl;
}

__global__ void scan2_kernel(int* bsums, int nb) {
    int lane = threadIdx.x;
    int v = (lane < nb) ? bsums[lane] : 0;
    int x = v;
#pragma unroll
    for (int o = 1; o < 64; o <<= 1) { int y = __shfl_up(x, o); if (lane >= o) x += y; }
    if (lane < nb) bsums[lane] = x - v;
}

__global__ __launch_bounds__(1024) void scan3_kernel(int* __restrict__ a,
                                                     const int* __restrict__ bsums, int n) {
    int i = blockIdx.x * 1024 + threadIdx.x;
    if (i < n) a[i] += bsums[blockIdx.x];
}

__global__ __launch_bounds__(256) void bin_scatter_kernel(const int* __restrict__ ei,
                                                          const int* __restrict__ cex,
                                                          int2* __restrict__ tmp, int E) {
    __shared__ int cur[NBUK];
    int tid = threadIdx.x;
    if (tid < NBUK) cur[tid] = cex[tid * GBIN + blockIdx.x];
    __syncthreads();
    for (int e = blockIdx.x * 256 + tid; e < E; e += GBIN * 256) {
        int src = ei[e];
        int dst = ei[E + e];
        int p = atomicAdd(&cur[dst >> BSHIFT], 1);
        tmp[p] = make_int2(src, dst);
    }
}

__global__ __launch_bounds__(256) void bucketize_kernel(const int2* __restrict__ tmp,
                                                        const int* __restrict__ cex,
                                                        int* __restrict__ row_ptr,
                                                        int* __restrict__ csr_src,
                                                        int n, int E) {
    __shared__ int hist[256];
    __shared__ int cur[256];
    __shared__ int stage[CAP];
    int b = blockIdx.x, tid = threadIdx.x;
    int bstart = cex[b * GBIN];
    int bend = (b == NBUK - 1) ? E : cex[(b + 1) * GBIN];
    int cnt = bend - bstart;
    int node_base = b << BSHIFT;

    hist[tid] = 0;
    __syncthreads();
    for (int i = tid; i < cnt; i += 256)
        atomicAdd(&hist[tmp[bstart + i].y - node_base], 1);
    __syncthreads();
    int v = hist[tid];
#pragma unroll
    for (int o = 1; o < 256; o <<= 1) {
        __syncthreads();
        int y = (tid >= o) ? hist[tid - o] : 0;
        __syncthreads();
        hist[tid] += y;
    }
    __syncthreads();
    int excl = hist[tid] - v;
    cur[tid] = excl;
    int node = node_base + tid;
    if (node < n) row_ptr[node] = bstart + excl;
    if (b == NBUK - 1 && tid == 0) row_ptr[n] = E;
    __syncthreads();

    if (cnt <= CAP) {
        for (int i = tid; i < cnt; i += 256) {
            int2 p = tmp[bstart + i];
            int slot = atomicAdd(&cur[p.y - node_base], 1);
            stage[slot] = p.x;
        }
        __syncthreads();
        for (int i = tid; i < cnt; i += 256)
            csr_src[bstart + i] = stage[i];
    } else {
        for (int i = tid; i < cnt; i += 256) {
            int2 p = tmp[bstart + i];
            int slot = atomicAdd(&cur[p.y - node_base], 1);
            csr_src[bstart + slot] = p.x;
        }
    }
}

// ---------------- dense GEMMs: t(bf16) = h@Wnbr ; u = h@Wself + b ----------------
__global__ __launch_bounds__(256) void gemm2_kernel(const float* __restrict__ h,
                                                    const float* __restrict__ Wnbr,
                                                    const float* __restrict__ Wself,
                                                    const float* __restrict__ bias,
                                                    unsigned short* __restrict__ tbf,
                                                    float* __restrict__ u, int n) {
    int lane = threadIdx.x & 63;
    float wn[64], ws[64];
#pragma unroll
    for (int k = 0; k < 64; ++k) {
        wn[k] = Wnbr[k * 64 + lane];
        ws[k] = Wself[k * 64 + lane];
    }
    float bv = bias[lane];
    int wave = (blockIdx.x * 256 + threadIdx.x) >> 6;
    int nwaves = gridDim.x * 4;
    // zero padding row N (gather target for inactive lanes)
    if (wave == 0) tbf[(size_t)n * 64 + lane] = 0;
    for (int i = wave; i < n; i += nwaves) {
        float hv = h[i * 64 + lane];
        float tacc = 0.f, uacc = bv;
#pragma unroll
        for (int k = 0; k < 64; ++k) {
            float hk = bcastf(hv, k);
            tacc = fmaf(hk, wn[k], tacc);
            uacc = fmaf(hk, ws[k], uacc);
        }
        tbf[(size_t)i * 64 + lane] = f2bf(tacc);
        u[(size_t)i * 64 + lane] = uacc;
    }
}

// ---------------- gather-aggregate + epilogue ----------------
// one wave per dst node; 4 edge-groups x 16 lanes; lane covers 4 channels (q*4..q*4+3)
// t rows are bf16; inactive slots point at zero row N.
__global__ __launch_bounds__(256) void agg_kernel(const unsigned short* __restrict__ tbf,
                                                  const float* __restrict__ u,
                                                  const int* __restrict__ row_ptr,
                                                  const int* __restrict__ csr_src,
                                                  float* __restrict__ out, int n, int use_mean) {
    int lane = threadIdx.x & 63;
    int g = lane >> 4;          // edge subgroup 0..3
    int q = lane & 15;          // channel quad
    int node = (blockIdx.x * 256 + threadIdx.x) >> 6;
    if (node >= n) return;
    int start = row_ptr[node];
    int end = row_ptr[node + 1];
    float4 acc = make_float4(0.f, 0.f, 0.f, 0.f);
    int e = start;
    while (e < end) {
        int cnt = end - e;
        if (cnt > 64) cnt = 64;
        int idx = (lane < cnt) ? csr_src[e + lane] : n;   // n -> zero row
        int cnt4 = (cnt + 3) & ~3;
        for (int j = 0; j < cnt4; j += 4) {
            int sidx = __shfl(idx, j + g);
            const uint2 w = *(const uint2*)(tbf + (size_t)sidx * 64 + q * 4);
            acc.x += __uint_as_float(w.x << 16);
            acc.y += __uint_as_float(w.x & 0xffff0000u);
            acc.z += __uint_as_float(w.y << 16);
            acc.w += __uint_as_float(w.y & 0xffff0000u);
        }
        e += cnt;
    }
    // reduce across the 4 edge-groups (lanes xor 16, xor 32)
    acc.x += __shfl_xor(acc.x, 16); acc.y += __shfl_xor(acc.y, 16);
    acc.z += __shfl_xor(acc.z, 16); acc.w += __shfl_xor(acc.w, 16);
    acc.x += __shfl_xor(acc.x, 32); acc.y += __shfl_xor(acc.y, 32);
    acc.z += __shfl_xor(acc.z, 32); acc.w += __shfl_xor(acc.w, 32);

    float scale = 1.f;
    if (use_mean) scale = 1.f / fmaxf((float)(end - start), 1.f);
    if (g == 0) {
        const float4 uv = *(const float4*)(u + (size_t)node * 64 + q * 4);
        float4 r;
        r.x = fmaxf(uv.x + acc.x * scale, 0.f);
        r.y = fmaxf(uv.y + acc.y * scale, 0.f);
        r.z = fmaxf(uv.z + acc.z * scale, 0.f);
        r.w = fmaxf(uv.w + acc.w * scale, 0.f);
        *(float4*)(out + (size_t)node * 64 + q * 4) = r;
    }
}

// ---------------- launch ----------------

extern "C" void kernel_launch(void* const* d_in, const int* in_sizes, int n_in,
                              void* d_out, int out_size, void* d_ws, size_t ws_size,
                              hipStream_t stream) {
    const float* x      = (const float*)d_in[0];
    const int*   ei     = (const int*)d_in[1];   // [2, E] int32
    const float* Wrel1  = (const float*)d_in[2];
    const float* Wroot1 = (const float*)d_in[3];
    const float* b1     = (const float*)d_in[4];
    const float* Wself2 = (const float*)d_in[5];
    const float* Wnbr2  = (const float*)d_in[6];
    const float* b2     = (const float*)d_in[7];
    const float* Wself3 = (const float*)d_in[8];
    const float* Wnbr3  = (const float*)d_in[9];
    const float* b3     = (const float*)d_in[10];
    const float* Wself4 = (const float*)d_in[11];
    const float* Wnbr4  = (const float*)d_in[12];
    const float* b4     = (const float*)d_in[13];

    const int N = N_NODES, E = N_EDGES;

    auto align = [](size_t o) { return (o + 255) & ~(size_t)255; };
    char* base = (char*)d_ws;
    size_t off = 0;
    int* counts  = (int*)(base + off); off = align(off + (size_t)NCOUNT * 4);
    int* cex     = (int*)(base + off); off = align(off + (size_t)NCOUNT * 4);
    int* bsums   = (int*)(base + off); off = align(off + 64 * 4);
    int* row_ptr = (int*)(base + off); off = align(off + (size_t)(N + 1) * 4);
    int* csr_src = (int*)(base + off); off = align(off + (size_t)E * 4);
    unsigned short* tbf = (unsigned short*)(base + off); off = align(off + (size_t)(N + 1) * 64 * 2);
    float* u  = (float*)(base + off); off = align(off + (size_t)N * 64 * 4);
    float* h1 = (float*)(base + off); off = align(off + (size_t)N * 64 * 4);
    int2* tmp = (int2*)h1;  // alias: tmp dead before h1's first write (agg layer 1)

    float* out1 = (float*)d_out;                      // x_1
    float* out2 = (float*)d_out + (size_t)N * 64;     // x_2

    // ---- CSR build ----
    bin_count_kernel<<<GBIN, 256, 0, stream>>>(ei, counts, E);
    int nb = (NCOUNT + 1023) / 1024;  // 49 <= 64
    scan1_kernel<<<nb, 1024, 0, stream>>>(counts, cex, bsums, NCOUNT);
    scan2_kernel<<<1, 64, 0, stream>>>(bsums, nb);
    scan3_kernel<<<nb, 1024, 0, stream>>>(cex, bsums, NCOUNT);
    bin_scatter_kernel<<<GBIN, 256, 0, stream>>>(ei, cex, tmp, E);
    bucketize_kernel<<<NBUK, 256, 0, stream>>>(tmp, cex, row_ptr, csr_src, N, E);

    const int GB = 768;            // gemm blocks (3072 waves)
    const int AB = (N + 3) / 4;    // 12500 blocks = 50000 waves

    // Layer 1 (RGCN): u = x@W_root1 + b1 ; t = x@W_rel1 ; mean aggregate
    gemm2_kernel<<<GB, 256, 0, stream>>>(x, Wrel1, Wroot1, b1, tbf, u, N);
    agg_kernel<<<AB, 256, 0, stream>>>(tbf, u, row_ptr, csr_src, h1, N, 1);
    // Layer 2 (GraphConv) -> x_1
    gemm2_kernel<<<GB, 256, 0, stream>>>(h1, Wnbr2, Wself2, b2, tbf, u, N);
    agg_kernel<<<AB, 256, 0, stream>>>(tbf, u, row_ptr, csr_src, out1, N, 0);
    // Layer 3
    gemm2_kernel<<<GB, 256, 0, stream>>>(out1, Wnbr3, Wself3, b3, tbf, u, N);
    agg_kernel<<<AB, 256, 0, stream>>>(tbf, u, row_ptr, csr_src, h1, N, 0);
    // Layer 4 -> x_2
    gemm2_kernel<<<GB, 256, 0, stream>>>(h1, Wnbr4, Wself4, b4, tbf, u, N);
    agg_kernel<<<AB, 256, 0, stream>>>(tbf, u, row_ptr, csr_src, out2, N, 0);
}

// Round 4
// 326.383 us; speedup vs baseline: 1.6528x; 1.1001x over previous
//
#include <hip/hip_runtime.h>

#define N_NODES 50000
#define HIDDEN  64
#define N_EDGES 1200000

#define BSHIFT 8                      // 256 nodes per bucket
#define NBUK   196                    // ceil(50000/256)
#define GBIN   256                    // blocks for scatter
#define PAD    8192                   // padded edge capacity per bucket (avg 6122, 26 sigma)

__device__ __forceinline__ float bcastf(float v, int k) {
    return __int_as_float(__builtin_amdgcn_readlane(__float_as_int(v), k));
}

// f32 -> bf16 (RNE) as ushort
__device__ __forceinline__ unsigned short f2bf(float x) {
    unsigned u = __float_as_uint(x);
    u += 0x7fffu + ((u >> 16) & 1u);
    return (unsigned short)(u >> 16);
}

__device__ __forceinline__ float bfl(unsigned w) { return __uint_as_float(w << 16); }
__device__ __forceinline__ float bfh(unsigned w) { return __uint_as_float(w & 0xffff0000u); }

// ---------------- bucketed CSR build (padded layout, no global scan) ----------------

__global__ void init_kernel(int* __restrict__ cursor) {
    int tid = threadIdx.x;
    if (tid < NBUK) cursor[tid] = tid * PAD;
}

// fused: per-block LDS hist -> one global reservation per (block,bucket) -> LDS-cursor scatter
__global__ __launch_bounds__(256) void scatter_fused_kernel(const int* __restrict__ ei,
                                                            int* __restrict__ cursor,
                                                            int2* __restrict__ tmp, int E) {
    __shared__ int h[NBUK];
    __shared__ int cur[NBUK];
    int tid = threadIdx.x;
    if (tid < NBUK) h[tid] = 0;
    __syncthreads();
    for (int e = blockIdx.x * 256 + tid; e < E; e += GBIN * 256)
        atomicAdd(&h[ei[E + e] >> BSHIFT], 1);
    __syncthreads();
    if (tid < NBUK) cur[tid] = atomicAdd(&cursor[tid], h[tid]);
    __syncthreads();
    for (int e = blockIdx.x * 256 + tid; e < E; e += GBIN * 256) {
        int src = ei[e];
        int dst = ei[E + e];
        int p = atomicAdd(&cur[dst >> BSHIFT], 1);
        tmp[p] = make_int2(src, dst);
    }
}

// one block per bucket: local hist -> row_info(start,deg), LDS counting sort -> csr_src
__global__ __launch_bounds__(256) void bucketize_kernel(const int2* __restrict__ tmp,
                                                        const int* __restrict__ cursor,
                                                        int2* __restrict__ row_info,
                                                        int* __restrict__ csr_src, int n) {
    __shared__ int hist[256];
    __shared__ int cur[256];
    __shared__ int stage[PAD];
    int b = blockIdx.x, tid = threadIdx.x;
    int base = b * PAD;
    int count = cursor[b] - base;          // cursor ended at base + count
    int node_base = b << BSHIFT;

    hist[tid] = 0;
    __syncthreads();
    for (int i = tid; i < count; i += 256)
        atomicAdd(&hist[tmp[base + i].y - node_base], 1);
    __syncthreads();
    int v = hist[tid];
#pragma unroll
    for (int o = 1; o < 256; o <<= 1) {    // Hillis-Steele inclusive scan
        __syncthreads();
        int y = (tid >= o) ? hist[tid - o] : 0;
        __syncthreads();
        hist[tid] += y;
    }
    __syncthreads();
    int excl = hist[tid] - v;
    cur[tid] = excl;
    int node = node_base + tid;
    if (node < n) row_info[node] = make_int2(base + excl, v);
    __syncthreads();
    for (int i = tid; i < count; i += 256) {
        int2 p = tmp[base + i];
        int slot = atomicAdd(&cur[p.y - node_base], 1);
        stage[slot] = p.x;
    }
    __syncthreads();
    for (int i = tid; i < count; i += 256)
        csr_src[base + i] = stage[i];
}

// ---------------- dense GEMMs: t(bf16) = h@Wnbr ; u = h@Wself + b ----------------
__global__ __launch_bounds__(256) void gemm2_kernel(const float* __restrict__ h,
                                                    const float* __restrict__ Wnbr,
                                                    const float* __restrict__ Wself,
                                                    const float* __restrict__ bias,
                                                    unsigned short* __restrict__ tbf,
                                                    float* __restrict__ u, int n) {
    int lane = threadIdx.x & 63;
    float wn[64], ws[64];
#pragma unroll
    for (int k = 0; k < 64; ++k) {
        wn[k] = Wnbr[k * 64 + lane];
        ws[k] = Wself[k * 64 + lane];
    }
    float bv = bias[lane];
    int wave = (blockIdx.x * 256 + threadIdx.x) >> 6;
    int nwaves = gridDim.x * 4;
    // zero padding row N (gather target for inactive lanes)
    if (wave == 0) tbf[(size_t)n * 64 + lane] = 0;
    for (int i = wave; i < n; i += nwaves) {
        float hv = h[i * 64 + lane];
        float tacc = 0.f, uacc = bv;
#pragma unroll
        for (int k = 0; k < 64; ++k) {
            float hk = bcastf(hv, k);
            tacc = fmaf(hk, wn[k], tacc);
            uacc = fmaf(hk, ws[k], uacc);
        }
        tbf[(size_t)i * 64 + lane] = f2bf(tacc);
        u[(size_t)i * 64 + lane] = uacc;
    }
}

// ---------------- gather-aggregate + epilogue ----------------
// one wave per dst node; 4 edge-groups x 16 lanes; lane covers channels q*4..q*4+3.
// 16 edges per iteration: 4 independent uint2 loads -> 4 independent accumulators (MLP=4).
__global__ __launch_bounds__(256) void agg_kernel(const unsigned short* __restrict__ tbf,
                                                  const float* __restrict__ u,
                                                  const int2* __restrict__ row_info,
                                                  const int* __restrict__ csr_src,
                                                  float* __restrict__ out, int n, int use_mean) {
    int lane = threadIdx.x & 63;
    int g = lane >> 4;          // edge subgroup 0..3
    int q = lane & 15;          // channel quad
    int node = (blockIdx.x * 256 + threadIdx.x) >> 6;
    if (node >= n) return;
    int2 ri = row_info[node];
    int start = ri.x, deg = ri.y;
    float4 a0 = {0,0,0,0}, a1 = {0,0,0,0}, a2 = {0,0,0,0}, a3 = {0,0,0,0};
    for (int e = 0; e < deg; e += 64) {
        int cnt = deg - e;
        if (cnt > 64) cnt = 64;
        int idx = (lane < cnt) ? csr_src[start + e + lane] : n;   // n -> zero row (L1-hot)
        int cnt16 = (cnt + 15) & ~15;
        for (int j = 0; j < cnt16; j += 16) {
            int s0 = __shfl(idx, j + g);
            int s1 = __shfl(idx, j + 4 + g);
            int s2 = __shfl(idx, j + 8 + g);
            int s3 = __shfl(idx, j + 12 + g);
            const uint2 w0 = *(const uint2*)(tbf + (size_t)s0 * 64 + q * 4);
            const uint2 w1 = *(const uint2*)(tbf + (size_t)s1 * 64 + q * 4);
            const uint2 w2 = *(const uint2*)(tbf + (size_t)s2 * 64 + q * 4);
            const uint2 w3 = *(const uint2*)(tbf + (size_t)s3 * 64 + q * 4);
            a0.x += bfl(w0.x); a0.y += bfh(w0.x); a0.z += bfl(w0.y); a0.w += bfh(w0.y);
            a1.x += bfl(w1.x); a1.y += bfh(w1.x); a1.z += bfl(w1.y); a1.w += bfh(w1.y);
            a2.x += bfl(w2.x); a2.y += bfh(w2.x); a2.z += bfl(w2.y); a2.w += bfh(w2.y);
            a3.x += bfl(w3.x); a3.y += bfh(w3.x); a3.z += bfl(w3.y); a3.w += bfh(w3.y);
        }
    }
    float4 acc;
    acc.x = (a0.x + a1.x) + (a2.x + a3.x);
    acc.y = (a0.y + a1.y) + (a2.y + a3.y);
    acc.z = (a0.z + a1.z) + (a2.z + a3.z);
    acc.w = (a0.w + a1.w) + (a2.w + a3.w);
    // reduce across the 4 edge-groups (butterfly: all lanes end with the total)
    acc.x += __shfl_xor(acc.x, 16); acc.y += __shfl_xor(acc.y, 16);
    acc.z += __shfl_xor(acc.z, 16); acc.w += __shfl_xor(acc.w, 16);
    acc.x += __shfl_xor(acc.x, 32); acc.y += __shfl_xor(acc.y, 32);
    acc.z += __shfl_xor(acc.z, 32); acc.w += __shfl_xor(acc.w, 32);

    float scale = 1.f;
    if (use_mean) scale = 1.f / fmaxf((float)deg, 1.f);
    if (g == 0) {
        const float4 uv = *(const float4*)(u + (size_t)node * 64 + q * 4);
        float4 r;
        r.x = fmaxf(uv.x + acc.x * scale, 0.f);
        r.y = fmaxf(uv.y + acc.y * scale, 0.f);
        r.z = fmaxf(uv.z + acc.z * scale, 0.f);
        r.w = fmaxf(uv.w + acc.w * scale, 0.f);
        *(float4*)(out + (size_t)node * 64 + q * 4) = r;
    }
}

// ---------------- launch ----------------

extern "C" void kernel_launch(void* const* d_in, const int* in_sizes, int n_in,
                              void* d_out, int out_size, void* d_ws, size_t ws_size,
                              hipStream_t stream) {
    const float* x      = (const float*)d_in[0];
    const int*   ei     = (const int*)d_in[1];   // [2, E] int32
    const float* Wrel1  = (const float*)d_in[2];
    const float* Wroot1 = (const float*)d_in[3];
    const float* b1     = (const float*)d_in[4];
    const float* Wself2 = (const float*)d_in[5];
    const float* Wnbr2  = (const float*)d_in[6];
    const float* b2     = (const float*)d_in[7];
    const float* Wself3 = (const float*)d_in[8];
    const float* Wnbr3  = (const float*)d_in[9];
    const float* b3     = (const float*)d_in[10];
    const float* Wself4 = (const float*)d_in[11];
    const float* Wnbr4  = (const float*)d_in[12];
    const float* b4     = (const float*)d_in[13];

    const int N = N_NODES, E = N_EDGES;

    auto align = [](size_t o) { return (o + 255) & ~(size_t)255; };
    char* base = (char*)d_ws;
    size_t off = 0;
    int*  cursor   = (int*)(base + off);  off = align(off + 256 * 4);
    int2* row_info = (int2*)(base + off); off = align(off + (size_t)N * 8);
    int*  csr_src  = (int*)(base + off);  off = align(off + (size_t)NBUK * PAD * 4);
    int2* tmp      = (int2*)(base + off); off = align(off + (size_t)NBUK * PAD * 8);
    unsigned short* tbf = (unsigned short*)(base + off); off = align(off + (size_t)(N + 1) * 64 * 2);
    float* u  = (float*)(base + off); off = align(off + (size_t)N * 64 * 4);
    float* h1 = (float*)(base + off); off = align(off + (size_t)N * 64 * 4);

    float* out1 = (float*)d_out;                      // x_1
    float* out2 = (float*)d_out + (size_t)N * 64;     // x_2

    // ---- CSR build: 3 dispatches ----
    init_kernel<<<1, 256, 0, stream>>>(cursor);
    scatter_fused_kernel<<<GBIN, 256, 0, stream>>>(ei, cursor, tmp, E);
    bucketize_kernel<<<NBUK, 256, 0, stream>>>(tmp, cursor, row_info, csr_src, N);

    const int GB = 768;            // gemm blocks (3072 waves)
    const int AB = (N + 3) / 4;    // 12500 blocks = 50000 waves

    // Layer 1 (RGCN): u = x@W_root1 + b1 ; t = x@W_rel1 ; mean aggregate
    gemm2_kernel<<<GB, 256, 0, stream>>>(x, Wrel1, Wroot1, b1, tbf, u, N);
    agg_kernel<<<AB, 256, 0, stream>>>(tbf, u, row_info, csr_src, h1, N, 1);
    // Layer 2 (GraphConv) -> x_1
    gemm2_kernel<<<GB, 256, 0, stream>>>(h1, Wnbr2, Wself2, b2, tbf, u, N);
    agg_kernel<<<AB, 256, 0, stream>>>(tbf, u, row_info, csr_src, out1, N, 0);
    // Layer 3
    gemm2_kernel<<<GB, 256, 0, stream>>>(out1, Wnbr3, Wself3, b3, tbf, u, N);
    agg_kernel<<<AB, 256, 0, stream>>>(tbf, u, row_info, csr_src, h1, N, 0);
    // Layer 4 -> x_2
    gemm2_kernel<<<GB, 256, 0, stream>>>(h1, Wnbr4, Wself4, b4, tbf, u, N);
    agg_kernel<<<AB, 256, 0, stream>>>(tbf, u, row_info, csr_src, out2, N, 0);
}